// Round 13
// baseline (327.462 us; speedup 1.0000x reference)
//
#include <hip/hip_runtime.h>
#include <hip/hip_fp16.h>

typedef _Float16 f16x8 __attribute__((ext_vector_type(8)));
typedef _Float16 f16x4 __attribute__((ext_vector_type(4)));
typedef _Float16 f16x2 __attribute__((ext_vector_type(2)));
typedef float    f32x16 __attribute__((ext_vector_type(16)));
typedef float    f32x4 __attribute__((ext_vector_type(4)));

#define SH 264   // H row stride (f16): 528 B; 528 mod 128 = 16 -> banks spread
#define SE 56    // E row stride (f16): 112 B; 112 mod 128 = 112 -> banks spread
#define PTS 64   // points per block: LDS 40960 B -> 3 blocks/CU

struct LayerPtrs {
  const float* w[8];
  const float* b[8];
};

// Weight fragments in d_ws, A-operand layout for mfma_f32_32x32x16_f16:
//   m = mtile*32 + (lane&31), k = kc*16 + (lane>>5)*8 + j ; value = W[k][m]
// index = WOFF[l] + (kc*8 + mtile)*64 + lane, element j.
__global__ void prep_weights(LayerPtrs P, f16x8* __restrict__ wf) {
  int gid = blockIdx.x * 256 + threadIdx.x;
  if (gid >= 60416) return;
  const int OFF[9] = {0,1536,9728,17920,26112,35840,44032,52224,60416};
  int l = 0;
  while (gid >= OFF[l+1]) ++l;
  int f = gid - OFF[l];
  int lane = f & 63;
  int t = f >> 6;
  int mtile = t & 7;
  int kc = t >> 3;
  int col = mtile * 32 + (lane & 31);
  int kb  = (lane >> 5) * 8;
  const float* w = P.w[l];
  f16x8 v;
#pragma unroll
  for (int j = 0; j < 8; ++j) {
    float x = 0.f;
    if (l == 4) {
      if (kc < 3) {
        int k = kc * 16 + kb + j;
        if (k < 39) x = w[k * 256 + col];
      } else {
        int k = (kc - 3) * 16 + kb + j;
        x = w[(39 + k) * 256 + col];
      }
    } else if (l == 0) {
      int k = kc * 16 + kb + j;
      if (k < 39) x = w[k * 256 + col];
    } else {
      int k = kc * 16 + kb + j;
      x = w[k * 256 + col];
    }
    v[j] = (_Float16)x;
  }
  wf[gid] = v;
}

#define MFMA __builtin_amdgcn_mfma_f32_32x32x16_f16

// A-pair load via inline asm: WE own the loads so WE own the waits (r7 core
// win: 52->60 MfmaUtil). r8 lesson: asm loads fully drained (vmcnt(0)) at mm
// exit, BEFORE any compiler-tracked global load (bias) issues.
__device__ __forceinline__ void aload2(f16x8& d0, f16x8& d1, const f16x8* p) {
  asm volatile("global_load_dwordx4 %0, %2, off\n\t"
               "global_load_dwordx4 %1, %2, off offset:1024"
               : "=&v"(d0), "=&v"(d1)
               : "v"(p));
}

__device__ __forceinline__ void mfma4(f16x8 a0, f16x8 a1, f16x8 v0, f16x8 v1,
                                      f32x16 acc[2][2]) {
  acc[0][0] = MFMA(a0, v0, acc[0][0], 0, 0, 0);
  acc[0][1] = MFMA(a0, v1, acc[0][1], 0, 0, 0);
  acc[1][0] = MFMA(a1, v0, acc[1][0], 0, 0, 0);
  acc[1][1] = MFMA(a1, v1, acc[1][1], 0, 0, 0);
}

__device__ __forceinline__ void mfma4_z(f16x8 a0, f16x8 a1, f16x8 v0, f16x8 v1,
                                        f32x16 acc[2][2]) {
  const f32x16 z = {};
  acc[0][0] = MFMA(a0, v0, z, 0, 0, 0);
  acc[0][1] = MFMA(a0, v1, z, 0, 0, 0);
  acc[1][0] = MFMA(a1, v0, z, 0, 0, 0);
  acc[1][1] = MFMA(a1, v1, z, 0, 0, 0);
}

// Wave = 64 hidden (2 mt) x 64 points (2 nt): 4 MFMA per kc. A: asm loads,
// rotation DISTANCE-3 (4 MFMA/kc = ~128 cyc cover, 3 kc ~ 384 cyc > 225 cyc
// L2 latency). Counted waits: steady vmcnt(6); tail vmcnt(4)/(2)/(0).
// sched_barrier(0) after the wait pins MFMAs behind it (rule #18).
// V (LDS) distance-1 via compiler ds_read (lgkmcnt auto-handled).
// FIRST: kc0 uses zero C operand (bias added in epilogue).
template<int NKC, bool FIRST, int RSTRIDE>
__device__ __forceinline__ void mm(const f16x8* __restrict__ wb,
                                   const char* __restrict__ r0,
                                   f32x16 acc[2][2]) {
  f16x8 a00, a01, b00, b01, c00, c01;
  aload2(a00, a01, wb);                         // pair 0
  if (NKC > 1) aload2(b00, b01, wb + 512);      // pair 1
  if (NKC > 2) aload2(c00, c01, wb + 1024);     // pair 2
  f16x8 v0 = *(const f16x8*)(r0);
  f16x8 v1 = *(const f16x8*)(r0 + RSTRIDE);
#pragma unroll
  for (int kc = 0; kc < NKC; ++kc) {
    f16x8 na0, na1, nv0, nv1;
    if (kc + 3 < NKC) aload2(na0, na1, wb + (kc + 3) * 512);
    if (kc + 1 < NKC) {
      const char* rp = r0 + 32 * (kc + 1);
      nv0 = *(const f16x8*)(rp);
      nv1 = *(const f16x8*)(rp + RSTRIDE);
    }
    if (kc + 3 < NKC)      asm volatile("s_waitcnt vmcnt(6)");
    else if (kc + 2 < NKC) asm volatile("s_waitcnt vmcnt(4)");
    else if (kc + 1 < NKC) asm volatile("s_waitcnt vmcnt(2)");
    else                   asm volatile("s_waitcnt vmcnt(0)");
    __builtin_amdgcn_sched_barrier(0);
    if (FIRST && kc == 0) mfma4_z(a00, a01, v0, v1, acc);
    else                  mfma4 (a00, a01, v0, v1, acc);
    if (kc + 1 < NKC) {
      a00 = b00; a01 = b01; b00 = c00; b01 = c01;
      v0 = nv0; v1 = nv1;
    }
    if (kc + 3 < NKC) { c00 = na0; c01 = na1; }
  }
}

__device__ __forceinline__ f16x4 relu_cvt4(float a0, float a1, float a2, float a3) {
  f16x2 lo = __builtin_bit_cast(f16x2, __builtin_amdgcn_cvt_pkrtz(a0, a1));
  f16x2 hi = __builtin_bit_cast(f16x2, __builtin_amdgcn_cvt_pkrtz(a2, a3));
  union { f16x4 v; f16x2 h[2]; } u;
  u.h[0] = lo; u.h[1] = hi;
  f16x4 z = {};
  return __builtin_elementwise_max(u.v, z);
}

// C/D 32x32: col(point) = lane&31, row(hidden) = (reg&3) + 8*(reg>>2) + 4*(lane>>5)
// Epilogue adds bias (acc + b) before relu, then f16x4 store.
__device__ __forceinline__ void store_epi(f32x16 acc[2][2],
                                          const float* __restrict__ bias,
                                          int wg, int p0, int h,
                                          _Float16* __restrict__ Hs) {
#pragma unroll
  for (int mt = 0; mt < 2; ++mt) {
    int hb = wg * 64 + mt * 32 + 4 * h;
#pragma unroll
    for (int g = 0; g < 4; ++g) {
      f32x4 q = *(const f32x4*)&bias[hb + 8 * g];
#pragma unroll
      for (int nt = 0; nt < 2; ++nt) {
        f16x4 o = relu_cvt4(acc[mt][nt][4 * g + 0] + q[0],
                            acc[mt][nt][4 * g + 1] + q[1],
                            acc[mt][nt][4 * g + 2] + q[2],
                            acc[mt][nt][4 * g + 3] + q[3]);
        *(f16x4*)&Hs[(nt * 32 + p0) * SH + hb + 8 * g] = o;
      }
    }
  }
}

__device__ __forceinline__ void emb_channel(_Float16* __restrict__ Erow,
                                            int c, float x) {
  _Float16 sv[6], cv[6];
  float fr = 1.f;
#pragma unroll
  for (int k = 0; k < 6; ++k) {
    float e = x * fr;
    sv[k] = (_Float16)__sinf(e);
    cv[k] = (_Float16)__cosf(e);
    fr *= 2.f;
  }
#pragma unroll
  for (int k = 0; k < 6; k += 2) {
    f16x2 s2 = {sv[k], sv[k + 1]};
    f16x2 c2 = {cv[k], cv[k + 1]};
    *(f16x2*)&Erow[6 * c + k]      = s2;
    *(f16x2*)&Erow[18 + 6 * c + k] = c2;
  }
  Erow[36 + c] = (_Float16)x;
}

// 256 threads = 4 waves: wave wg owns hidden slice [64wg, 64wg+64) for all
// 64 points. LDS: H 64xSH f16 (33792 B) + E 64xSE f16 (7168 B) = 40960 B.
//
// ROUND-13 STRUCTURE: 3 blocks/CU (launch_bounds(256,3); 3x40960 = 122.9KB
// of 160KB LDS). 12 waves/CU at three independently-drifting block phases:
// when one block is in its epilogue/barrier window the other two are mid-mm
// and keep the MFMA pipe fed. This is r10's phase-offset mechanism (which
// raised MfmaUtil 59.6->61.9 but paid for itself in sleep cycles) realized
// with real work instead of sleep. In-place H, 2 barriers/layer (r7 style;
// r12 proved ping-pong's barrier halving loses to its LDS cost).
// VGPR budget at 3 waves/SIMD = ~168; r12's identical shape compiled to
// 88 arch + 64 acc = 152.
__global__ __launch_bounds__(256, 3)
void mlp_fused(const float* __restrict__ points,
               LayerPtrs P,
               const f16x8* __restrict__ wf,
               const float* __restrict__ wsdf,
               const float* __restrict__ bsdf,
               float* __restrict__ out) {
  __shared__ __align__(16) _Float16 Hs[PTS * SH];   // 33792 B
  __shared__ __align__(16) _Float16 Es[PTS * SE];   //  7168 B
  const int tid = threadIdx.x;
  const int blk = blockIdx.x;

  const int lane = tid & 63;
  const int wg   = tid >> 6;
  const int p0   = lane & 31;
  const int h    = lane >> 5;

  // frag(l, kc, mt) = wb[WOFF[l] + kc*512 + mt*64]; wave owns mtiles 2wg, 2wg+1
  const f16x8* wb = wf + wg * 128 + lane;

  // ---- embedding: wave-uniform split. wave c in {0,1,2} -> channel c for
  // all 64 points; wave 3 -> zero pad cols 39..55.
  {
    int p = tid & 63, part = tid >> 6;
    _Float16* Erow = &Es[p * SE];
    if (part < 3) {
      emb_channel(Erow, part, points[(blk * PTS + p) * 3 + part]);
    } else {
      Erow[39] = (_Float16)0.f;
      f16x4 z4 = {};
      *(f16x4*)&Erow[40] = z4;
      *(f16x4*)&Erow[44] = z4;
      *(f16x4*)&Erow[48] = z4;
      *(f16x4*)&Erow[52] = z4;
    }
  }
  __syncthreads();

  const char* hR = (const char*)Hs + (p0 * SH + 8 * h) * 2;
  const char* eR = (const char*)Es + (p0 * SE + 8 * h) * 2;

  f32x16 acc[2][2];
  const int WOFF[8] = {0, 1536, 9728, 17920, 26112, 35840, 44032, 52224};

  // L0: read E, write H (disjoint -> no barrier between mm and store)
  mm<3, true, 32 * SE * 2>(wb, eR, acc);
  store_epi(acc, P.b[0], wg, p0, h, Hs);
  __syncthreads();

  // L1..L3: in-place H
#pragma unroll
  for (int l = 1; l < 4; ++l) {
    mm<16, true, 32 * SH * 2>(wb + WOFF[l], hR, acc);
    __syncthreads();
    store_epi(acc, P.b[l], wg, p0, h, Hs);
    __syncthreads();
  }

  // L4: concat input = E (3 kc, zero-C) + H (16 kc, accumulate)
  {
    mm<3, true, 32 * SE * 2>(wb + 26112, eR, acc);
    mm<16, false, 32 * SH * 2>(wb + 27648, hR, acc);
    __syncthreads();
    store_epi(acc, P.b[4], wg, p0, h, Hs);
    __syncthreads();
  }

  // L5..L6
#pragma unroll
  for (int l = 5; l < 7; ++l) {
    mm<16, true, 32 * SH * 2>(wb + WOFF[l], hR, acc);
    __syncthreads();
    store_epi(acc, P.b[l], wg, p0, h, Hs);
    __syncthreads();
  }

  // L7 + SDF head: out[p] = sum_h relu(x7 + b7)[p][h] * wsdf[h] + bsdf
  mm<16, true, 32 * SH * 2>(wb + WOFF[7], hR, acc);
  {
    float part0 = 0.f, part1 = 0.f;
    const float* b7 = P.b[7];
#pragma unroll
    for (int mt = 0; mt < 2; ++mt) {
#pragma unroll
      for (int g = 0; g < 4; ++g) {
        int idx = wg * 64 + mt * 32 + 8 * g + 4 * h;
        f32x4 qb = *(const f32x4*)&b7[idx];
        f32x4 qw = *(const f32x4*)&wsdf[idx];
#pragma unroll
        for (int r = 0; r < 4; ++r) {
          part0 += fmaxf(acc[mt][0][4 * g + r] + qb[r], 0.f) * qw[r];
          part1 += fmaxf(acc[mt][1][4 * g + r] + qb[r], 0.f) * qw[r];
        }
      }
    }
    // E space dead since L4 (barriers since) -> partial buffer PB[8][64]
    // floats (2 KB) in Es. L7 reads only Hs; no conflict.
    float* PB = (float*)Es;
    PB[(wg * 2 + h) * 64 + p0]      = part0;
    PB[(wg * 2 + h) * 64 + 32 + p0] = part1;
    __syncthreads();
    if (tid < PTS) {
      float s = bsdf[0];
#pragma unroll
      for (int j = 0; j < 8; ++j) s += PB[j * 64 + tid];
      out[blk * PTS + tid] = s;
    }
  }
}

extern "C" void kernel_launch(void* const* d_in, const int* in_sizes, int n_in,
                              void* d_out, int out_size, void* d_ws, size_t ws_size,
                              hipStream_t stream) {
  const float* points = (const float*)d_in[0];
  LayerPtrs P;
  for (int i = 0; i < 8; ++i) {
    P.w[i] = (const float*)d_in[1 + 2 * i];
    P.b[i] = (const float*)d_in[2 + 2 * i];
  }
  const float* wsdf = (const float*)d_in[17];
  const float* bsdf = (const float*)d_in[18];
  f16x8* wf = (f16x8*)d_ws;   // needs 966656 B

  int N = in_sizes[0] / 3;    // 262144
  prep_weights<<<236, 256, 0, stream>>>(P, wf);
  mlp_fused<<<N / PTS, 256, 0, stream>>>(points, P, wf, wsdf, bsdf, (float*)d_out);
}

// Round 16
// 290.733 us; speedup vs baseline: 1.1263x; 1.1263x over previous
//
#include <hip/hip_runtime.h>
#include <hip/hip_fp16.h>

typedef _Float16 f16x8 __attribute__((ext_vector_type(8)));
typedef _Float16 f16x4 __attribute__((ext_vector_type(4)));
typedef _Float16 f16x2 __attribute__((ext_vector_type(2)));
typedef float    f32x16 __attribute__((ext_vector_type(16)));
typedef float    f32x4 __attribute__((ext_vector_type(4)));

#define SH 264   // H row stride (f16): 528 B; 528 mod 128 = 16 -> banks spread
#define SE 56    // E row stride (f16): 112 B; 112 mod 128 = 112 -> banks spread

struct LayerPtrs {
  const float* w[8];
  const float* b[8];
};

// Weight fragments in d_ws, A-operand layout for mfma_f32_32x32x16_f16:
//   m = mtile*32 + (lane&31), k = kc*16 + (lane>>5)*8 + j ; value = W[k][m]
// index = WOFF[l] + (kc*8 + mtile)*64 + lane, element j.
__global__ void prep_weights(LayerPtrs P, f16x8* __restrict__ wf) {
  int gid = blockIdx.x * 256 + threadIdx.x;
  if (gid >= 60416) return;
  const int OFF[9] = {0,1536,9728,17920,26112,35840,44032,52224,60416};
  int l = 0;
  while (gid >= OFF[l+1]) ++l;
  int f = gid - OFF[l];
  int lane = f & 63;
  int t = f >> 6;
  int mtile = t & 7;
  int kc = t >> 3;
  int col = mtile * 32 + (lane & 31);
  int kb  = (lane >> 5) * 8;
  const float* w = P.w[l];
  f16x8 v;
#pragma unroll
  for (int j = 0; j < 8; ++j) {
    float x = 0.f;
    if (l == 4) {
      if (kc < 3) {
        int k = kc * 16 + kb + j;
        if (k < 39) x = w[k * 256 + col];
      } else {
        int k = (kc - 3) * 16 + kb + j;
        x = w[(39 + k) * 256 + col];
      }
    } else if (l == 0) {
      int k = kc * 16 + kb + j;
      if (k < 39) x = w[k * 256 + col];
    } else {
      int k = kc * 16 + kb + j;
      x = w[k * 256 + col];
    }
    v[j] = (_Float16)x;
  }
  wf[gid] = v;
}

#define MFMA __builtin_amdgcn_mfma_f32_32x32x16_f16

// A-pair load via inline asm: WE own the loads so WE own the waits.
// (r6/7 lesson: compiler-tracked rotated loads get conservative vmcnt
// drains -> full L2 latency exposed per kc; asm loads + counted vmcnt
// gave 52->60 MfmaUtil, 228->209us. r8 lesson: asm loads must be fully
// drained at mm exit, before any compiler-tracked global load issues.)
// mt stride = 64 f16x8 = 1024 B -> second load via offset imm.
__device__ __forceinline__ void aload2(f16x8& d0, f16x8& d1, const f16x8* p) {
  asm volatile("global_load_dwordx4 %0, %2, off\n\t"
               "global_load_dwordx4 %1, %2, off offset:1024"
               : "=&v"(d0), "=&v"(d1)
               : "v"(p));
}

// ROUND-15 (= r14, twice blocked by infra): s_setprio(1) around the MFMA
// cluster (T5), single variable vs r7 champion. r10 measured that
// co-resident blocks' phases partially align (forced de-alignment raised
// MfmaUtil 59.6->61.9 but paid in sleep); setprio gets the same arbitration
// preference -- mm-phase waves beat epilogue-phase waves for issue slots --
// at zero cycle cost. Never isolated before (r8 bundled it with a
// regression).
__device__ __forceinline__ void mfma8(f16x8 a0, f16x8 a1,
                                      f16x8 v0, f16x8 v1, f16x8 v2, f16x8 v3,
                                      f32x16 acc[2][4]) {
  __builtin_amdgcn_s_setprio(1);
  acc[0][0] = MFMA(a0, v0, acc[0][0], 0, 0, 0);
  acc[0][1] = MFMA(a0, v1, acc[0][1], 0, 0, 0);
  acc[0][2] = MFMA(a0, v2, acc[0][2], 0, 0, 0);
  acc[0][3] = MFMA(a0, v3, acc[0][3], 0, 0, 0);
  acc[1][0] = MFMA(a1, v0, acc[1][0], 0, 0, 0);
  acc[1][1] = MFMA(a1, v1, acc[1][1], 0, 0, 0);
  acc[1][2] = MFMA(a1, v2, acc[1][2], 0, 0, 0);
  acc[1][3] = MFMA(a1, v3, acc[1][3], 0, 0, 0);
  __builtin_amdgcn_s_setprio(0);
}

__device__ __forceinline__ void mfma8_z(f16x8 a0, f16x8 a1,
                                        f16x8 v0, f16x8 v1, f16x8 v2, f16x8 v3,
                                        f32x16 acc[2][4]) {
  const f32x16 z = {};
  __builtin_amdgcn_s_setprio(1);
  acc[0][0] = MFMA(a0, v0, z, 0, 0, 0);
  acc[0][1] = MFMA(a0, v1, z, 0, 0, 0);
  acc[0][2] = MFMA(a0, v2, z, 0, 0, 0);
  acc[0][3] = MFMA(a0, v3, z, 0, 0, 0);
  acc[1][0] = MFMA(a1, v0, z, 0, 0, 0);
  acc[1][1] = MFMA(a1, v1, z, 0, 0, 0);
  acc[1][2] = MFMA(a1, v2, z, 0, 0, 0);
  acc[1][3] = MFMA(a1, v3, z, 0, 0, 0);
  __builtin_amdgcn_s_setprio(0);
}

// Wave = 64 hidden (2 mt) x 128 points (4 nt): 8 MFMA per kc, per-wave
// DISTINCT weight slice. A: asm loads, rotation distance-2, counted waits:
//   steady: 4 newer loads in flight -> s_waitcnt vmcnt(4)
//   tail:   vmcnt(2) then vmcnt(0)   (all asm loads drained at mm exit)
// sched_barrier(0) after the wait pins the MFMAs behind it (rule #18).
// V (LDS) distance-1 via compiler ds_read (lgkmcnt auto-handled).
// FIRST: kc0 uses zero C operand (bias added in epilogue).
template<int NKC, bool FIRST, int RSTRIDE>
__device__ __forceinline__ void mm(const f16x8* __restrict__ wb,
                                   const char* __restrict__ r0,
                                   f32x16 acc[2][4]) {
  f16x8 a00, a01, a10, a11;
  aload2(a00, a01, wb);                        // pair 0
  if (NKC > 1) aload2(a10, a11, wb + 512);     // pair 1
  f16x8 v0 = *(const f16x8*)(r0);
  f16x8 v1 = *(const f16x8*)(r0 + RSTRIDE);
  f16x8 v2 = *(const f16x8*)(r0 + 2 * RSTRIDE);
  f16x8 v3 = *(const f16x8*)(r0 + 3 * RSTRIDE);
#pragma unroll
  for (int kc = 0; kc < NKC; ++kc) {
    f16x8 na0, na1, nv0, nv1, nv2, nv3;
    if (kc + 2 < NKC) aload2(na0, na1, wb + (kc + 2) * 512);
    if (kc + 1 < NKC) {
      const char* rp = r0 + 32 * (kc + 1);
      nv0 = *(const f16x8*)(rp);
      nv1 = *(const f16x8*)(rp + RSTRIDE);
      nv2 = *(const f16x8*)(rp + 2 * RSTRIDE);
      nv3 = *(const f16x8*)(rp + 3 * RSTRIDE);
    }
    if (kc + 2 < NKC)      asm volatile("s_waitcnt vmcnt(4)");
    else if (kc + 1 < NKC) asm volatile("s_waitcnt vmcnt(2)");
    else                   asm volatile("s_waitcnt vmcnt(0)");
    __builtin_amdgcn_sched_barrier(0);
    if (FIRST && kc == 0) mfma8_z(a00, a01, v0, v1, v2, v3, acc);
    else                  mfma8 (a00, a01, v0, v1, v2, v3, acc);
    if (kc + 1 < NKC) {
      a00 = a10; a01 = a11;
      v0 = nv0; v1 = nv1; v2 = nv2; v3 = nv3;
    }
    if (kc + 2 < NKC) { a10 = na0; a11 = na1; }
  }
}

__device__ __forceinline__ f16x4 relu_cvt4(float a0, float a1, float a2, float a3) {
  f16x2 lo = __builtin_bit_cast(f16x2, __builtin_amdgcn_cvt_pkrtz(a0, a1));
  f16x2 hi = __builtin_bit_cast(f16x2, __builtin_amdgcn_cvt_pkrtz(a2, a3));
  union { f16x4 v; f16x2 h[2]; } u;
  u.h[0] = lo; u.h[1] = hi;
  f16x4 z = {};
  return __builtin_elementwise_max(u.v, z);
}

// C/D 32x32: col(point) = lane&31, row(hidden) = (reg&3) + 8*(reg>>2) + 4*(lane>>5)
// Epilogue adds bias (acc + b) before relu, then f16x4 store.
__device__ __forceinline__ void store_epi(f32x16 acc[2][4],
                                          const float* __restrict__ bias,
                                          int wg, int p0, int h,
                                          _Float16* __restrict__ Hs) {
#pragma unroll
  for (int mt = 0; mt < 2; ++mt) {
    int hb = wg * 64 + mt * 32 + 4 * h;
#pragma unroll
    for (int g = 0; g < 4; ++g) {
      f32x4 q = *(const f32x4*)&bias[hb + 8 * g];
#pragma unroll
      for (int nt = 0; nt < 4; ++nt) {
        f16x4 o = relu_cvt4(acc[mt][nt][4 * g + 0] + q[0],
                            acc[mt][nt][4 * g + 1] + q[1],
                            acc[mt][nt][4 * g + 2] + q[2],
                            acc[mt][nt][4 * g + 3] + q[3]);
        *(f16x4*)&Hs[(nt * 32 + p0) * SH + hb + 8 * g] = o;
      }
    }
  }
}

__device__ __forceinline__ void emb_channel(_Float16* __restrict__ Erow,
                                            int c, float x) {
  _Float16 sv[6], cv[6];
  float fr = 1.f;
#pragma unroll
  for (int k = 0; k < 6; ++k) {
    float e = x * fr;
    sv[k] = (_Float16)__sinf(e);
    cv[k] = (_Float16)__cosf(e);
    fr *= 2.f;
  }
#pragma unroll
  for (int k = 0; k < 6; k += 2) {
    f16x2 s2 = {sv[k], sv[k + 1]};
    f16x2 c2 = {cv[k], cv[k + 1]};
    *(f16x2*)&Erow[6 * c + k]      = s2;
    *(f16x2*)&Erow[18 + 6 * c + k] = c2;
  }
  Erow[36 + c] = (_Float16)x;
}

// 256 threads = 4 waves: wave wg owns hidden slice [64wg, 64wg+64), all 128
// points. LDS: H 128xSH f16 (67584 B) + E 128xSE f16 (14336 B) = 81920 B
// -> 2 blocks/CU, 8 waves/CU (2/SIMD).
__global__ __launch_bounds__(256, 2)
void mlp_fused(const float* __restrict__ points,
               LayerPtrs P,
               const f16x8* __restrict__ wf,
               const float* __restrict__ wsdf,
               const float* __restrict__ bsdf,
               float* __restrict__ out) {
  __shared__ __align__(16) _Float16 Hs[128 * SH];   // 67584 B
  __shared__ __align__(16) _Float16 Es[128 * SE];   // 14336 B
  const int tid = threadIdx.x;
  const int blk = blockIdx.x;

  const int lane = tid & 63;
  const int wg   = tid >> 6;
  const int p0   = lane & 31;
  const int h    = lane >> 5;

  // frag(l, kc, mt) = wb[WOFF[l] + kc*512 + mt*64]; wave owns mtiles 2wg, 2wg+1
  const f16x8* wb = wf + wg * 128 + lane;

  // ---- embedding: 2 threads/point. part0 -> ch0,ch1; part1 -> ch2 + pad.
  // E cols: [sin(18) | cos(18) | xyz(3) | zeros 39..55]; row = point.
  {
    int p = tid & 127, part = tid >> 7;
    _Float16* Erow = &Es[p * SE];
    const float* pp = &points[(blk * 128 + p) * 3];
    if (part == 0) {
      emb_channel(Erow, 0, pp[0]);
      emb_channel(Erow, 1, pp[1]);
    } else {
      emb_channel(Erow, 2, pp[2]);
      Erow[39] = (_Float16)0.f;
      f16x4 z4 = {};
      *(f16x4*)&Erow[40] = z4;
      *(f16x4*)&Erow[44] = z4;
      *(f16x4*)&Erow[48] = z4;
      *(f16x4*)&Erow[52] = z4;
    }
  }
  __syncthreads();

  const char* hR = (const char*)Hs + (p0 * SH + 8 * h) * 2;
  const char* eR = (const char*)Es + (p0 * SE + 8 * h) * 2;

  f32x16 acc[2][4];

  // L0: read E, write H (disjoint -> no barrier between mm and store)
  mm<3, true, 32 * SE * 2>(wb, eR, acc);
  store_epi(acc, P.b[0], wg, p0, h, Hs);
  __syncthreads();

  const int WOFF[8] = {0, 1536, 9728, 17920, 26112, 35840, 44032, 52224};

  // L1..L3: in-place H
#pragma unroll
  for (int l = 1; l < 4; ++l) {
    mm<16, true, 32 * SH * 2>(wb + WOFF[l], hR, acc);
    __syncthreads();
    store_epi(acc, P.b[l], wg, p0, h, Hs);
    __syncthreads();
  }

  // L4: concat input = E (3 kc, zero-C) + H (16 kc, accumulate)
  {
    mm<3, true, 32 * SE * 2>(wb + 26112, eR, acc);
    mm<16, false, 32 * SH * 2>(wb + 27648, hR, acc);
    __syncthreads();
    store_epi(acc, P.b[4], wg, p0, h, Hs);
    __syncthreads();
  }

  // L5..L6
#pragma unroll
  for (int l = 5; l < 7; ++l) {
    mm<16, true, 32 * SH * 2>(wb + WOFF[l], hR, acc);
    __syncthreads();
    store_epi(acc, P.b[l], wg, p0, h, Hs);
    __syncthreads();
  }

  // L7 + SDF head: out[p] = sum_h relu(x7 + b7)[p][h] * wsdf[h] + bsdf
  mm<16, true, 32 * SH * 2>(wb + 52224, hR, acc);
  {
    float part[4] = {0.f, 0.f, 0.f, 0.f};
    const float* b7 = P.b[7];
#pragma unroll
    for (int mt = 0; mt < 2; ++mt) {
#pragma unroll
      for (int g = 0; g < 4; ++g) {
        int idx = wg * 64 + mt * 32 + 8 * g + 4 * h;
        f32x4 qb = *(const f32x4*)&b7[idx];
        f32x4 qw = *(const f32x4*)&wsdf[idx];
#pragma unroll
        for (int nt = 0; nt < 4; ++nt)
#pragma unroll
          for (int r = 0; r < 4; ++r)
            part[nt] += fmaxf(acc[mt][nt][4 * g + r] + qb[r], 0.f) * qw[r];
      }
    }
    // E space dead since L4 (block-wide barriers since) -> partial buffer
    // PB[8][128] floats (4 KB). PB writes touch only Es; L7 reads only Hs.
    float* PB = (float*)Es;
#pragma unroll
    for (int nt = 0; nt < 4; ++nt)
      PB[(wg * 2 + h) * 128 + nt * 32 + p0] = part[nt];
    __syncthreads();
    if (tid < 128) {
      float s = bsdf[0];
#pragma unroll
      for (int j = 0; j < 8; ++j) s += PB[j * 128 + tid];
      out[blk * 128 + tid] = s;
    }
  }
}

extern "C" void kernel_launch(void* const* d_in, const int* in_sizes, int n_in,
                              void* d_out, int out_size, void* d_ws, size_t ws_size,
                              hipStream_t stream) {
  const float* points = (const float*)d_in[0];
  LayerPtrs P;
  for (int i = 0; i < 8; ++i) {
    P.w[i] = (const float*)d_in[1 + 2 * i];
    P.b[i] = (const float*)d_in[2 + 2 * i];
  }
  const float* wsdf = (const float*)d_in[17];
  const float* bsdf = (const float*)d_in[18];
  f16x8* wf = (f16x8*)d_ws;   // needs 966656 B

  int N = in_sizes[0] / 3;    // 262144
  prep_weights<<<236, 256, 0, stream>>>(P, wf);
  mlp_fused<<<N / 128, 256, 0, stream>>>(points, P, wf, wsdf, bsdf, (float*)d_out);
}